// Round 4
// baseline (2627.374 us; speedup 1.0000x reference)
//
#include <hip/hip_runtime.h>
#include <math.h>

// Problem constants
#define NVEC  32768          // B*L = 64*512
#define DDIM  512            // CODE_DIM
#define KCB   4              // NUM_CODEBOOKS
#define SCB   1024           // CODEBOOK_SIZE
#define SUBD  128            // SUB_DIM

#define IDX_COUNT (NVEC * KCB)            // 131072
#define ZQ_COUNT  (NVEC * DDIM)           // 16777216
#define OFF_ZQ_ST  IDX_COUNT
#define OFF_ZQ_ALL (IDX_COUNT + ZQ_COUNT)
#define OFF_SCAL   (IDX_COUNT + 2 * ZQ_COUNT)

// Strict (non-contractable) f32 ops to replicate numpy's rounding exactly.
__device__ __forceinline__ float fmul(float a, float b) { return __fmul_rn(a, b); }
__device__ __forceinline__ float fadd(float a, float b) { return __fadd_rn(a, b); }
__device__ __forceinline__ float fsub(float a, float b) { return __fsub_rn(a, b); }

// numpy pairwise_sum for n=128 contiguous f32 (n <= PW_BLOCKSIZE, scalar
// 8-accumulator path): r[j] accumulates elements i with i%8==j sequentially,
// final combine ((r0+r1)+(r2+r3)) + ((r4+r5)+(r6+r7)).
// Here the elements are products u[i]*v[i], each individually f32-rounded
// (numpy squares/multiplies elementwise first, then sums).
__device__ __forceinline__ float np_dot128(const float* __restrict__ u,
                                           const float* __restrict__ v) {
  float r[8];
#pragma unroll
  for (int j = 0; j < 8; ++j) r[j] = fmul(u[j], v[j]);
#pragma unroll
  for (int i = 8; i < 128; i += 8) {
#pragma unroll
    for (int j = 0; j < 8; ++j) r[j] = fadd(r[j], fmul(u[i + j], v[i + j]));
  }
  return fadd(fadd(fadd(r[0], r[1]), fadd(r[2], r[3])),
              fadd(fadd(r[4], r[5]), fadd(r[6], r[7])));
}

// ---------------------------------------------------------------------------
// Kernel 1: per-(n,k) argmin over 1024 codes, replicating numpy float32:
//   dist_s = fl( fl( A - 2*E_s ) + C2_s ),  A=(x^2).sum  E_s=dot  C2_s=(c^2).sum
// Fast fma scan ranks candidates; np-exact f32 rescore of top-4 decides, with
// np.argmin first-index tie semantics.
// ---------------------------------------------------------------------------
__global__ __launch_bounds__(256) void k_argmin(
    const float* __restrict__ z_e, const float* __restrict__ cb,
    float* __restrict__ out_idx, int* __restrict__ counts) {
  const int k = blockIdx.y;
  const int n = blockIdx.x * 256 + threadIdx.x;
  const float* __restrict__ cbk = cb + (size_t)k * SCB * SUBD;

  // Approx ||c_s||^2 in LDS (ranking only; fma fine).
  __shared__ float c2s[SCB];
  for (int s = threadIdx.x; s < SCB; s += 256) {
    const float* c = cbk + s * SUBD;
    float a0 = 0.f, a1 = 0.f, a2 = 0.f, a3 = 0.f;
#pragma unroll
    for (int j = 0; j < SUBD; j += 4) {
      a0 = fmaf(c[j + 0], c[j + 0], a0);
      a1 = fmaf(c[j + 1], c[j + 1], a1);
      a2 = fmaf(c[j + 2], c[j + 2], a2);
      a3 = fmaf(c[j + 3], c[j + 3], a3);
    }
    c2s[s] = (a0 + a1) + (a2 + a3);
  }
  __syncthreads();

  // x (128 floats) into registers.
  float4 x[32];
  const float4* xp = (const float4*)(z_e + (size_t)n * DDIM + k * SUBD);
#pragma unroll
  for (int j = 0; j < 32; ++j) x[j] = xp[j];
  const float* xs = (const float*)x;

  // Fast approx scan (fma), track top-4 candidate indices.
  float m0 = 1e30f, m1 = 1e30f, m2 = 1e30f, m3 = 1e30f;
  int i0 = 0, i1 = 0, i2 = 0, i3 = 0;
  for (int s = 0; s < SCB; ++s) {
    const float4* c = (const float4*)(cbk + s * SUBD);
    float a0 = 0.f, a1 = 0.f, a2 = 0.f, a3 = 0.f;
#pragma unroll
    for (int j = 0; j < 32; ++j) {
      float4 cv = c[j];
      a0 = fmaf(x[j].x, cv.x, a0);
      a1 = fmaf(x[j].y, cv.y, a1);
      a2 = fmaf(x[j].z, cv.z, a2);
      a3 = fmaf(x[j].w, cv.w, a3);
    }
    const float score = fmaf(-2.0f, (a0 + a1) + (a2 + a3), c2s[s]);
    if (score < m3) {
      if (score < m0)      { m3=m2;i3=i2; m2=m1;i2=i1; m1=m0;i1=i0; m0=score;i0=s; }
      else if (score < m1) { m3=m2;i3=i2; m2=m1;i2=i1; m1=score;i1=s; }
      else if (score < m2) { m3=m2;i3=i2; m2=score;i2=s; }
      else                 { m3=score;i3=s; }
    }
  }

  // np-exact f32: A = pairwise8 sum of fl(x*x).
  const float A = np_dot128(xs, xs);

  // Rescore the 4 candidates with the exact np formula; first-index ties.
  const int cand[4] = {i0, i1, i2, i3};
  float bd = 1e30f;
  int bi = SCB;
#pragma unroll
  for (int t = 0; t < 4; ++t) {
    const float* c = cbk + cand[t] * SUBD;
    const float E = np_dot128(xs, c);
    const float C2 = np_dot128(c, c);
    const float dist = fadd(fsub(A, fmul(2.0f, E)), C2);
    if (dist < bd || (dist == bd && cand[t] < bi)) { bd = dist; bi = cand[t]; }
  }

  out_idx[(size_t)n * KCB + k] = (float)bi;
  atomicAdd(&counts[k * SCB + bi], 1);
}

// ---------------------------------------------------------------------------
// Kernel 2: perplexity from counts (runs before k_gather overwrites counts).
// ---------------------------------------------------------------------------
__global__ __launch_bounds__(256) void k_perp(const int* __restrict__ counts,
                                              float* __restrict__ out_perp) {
  const int w = threadIdx.x >> 6;
  const int lane = threadIdx.x & 63;
  double h = 0.0;
  for (int i = 0; i < SCB / 64; ++i) {
    const int cnt = counts[w * SCB + i * 64 + lane];
    if (cnt > 0) {
      const double p = (double)cnt * (1.0 / 32768.0);
      h += p * log(p);   // p >= 1/32768 > 1e-8, clip inactive
    }
  }
#pragma unroll
  for (int off = 32; off > 0; off >>= 1) h += __shfl_down(h, off, 64);
  __shared__ double hs[4];
  if (lane == 0) hs[w] = h;
  __syncthreads();
  if (threadIdx.x == 0) {
    double perp = 0.0;
    for (int w2 = 0; w2 < 4; ++w2) perp += exp(-hs[w2]);
    out_perp[0] = (float)(perp * 0.25);
  }
}

// ---------------------------------------------------------------------------
// Kernel 3: coalesced gather of z_q into both output slots + loss partial.
// ---------------------------------------------------------------------------
__global__ __launch_bounds__(256) void k_gather(
    const float* __restrict__ z_e, const float* __restrict__ cb,
    const float* __restrict__ idxf, float* __restrict__ zq_st,
    float* __restrict__ zq_all, float* __restrict__ loss_acc) {
  const int base = blockIdx.x * 4096;
  float local = 0.f;
#pragma unroll
  for (int i = 0; i < 16; ++i) {
    const int q = base + i * 256 + threadIdx.x;
    const int nn = q >> 7;         // 128 float4 per 512-float row
    const int rem = q & 127;
    const int kk = rem >> 5;
    const int j4 = rem & 31;
    const int idx = (int)idxf[nn * KCB + kk];
    const float4 v = ((const float4*)cb)[(size_t)(kk * SCB + idx) * 32 + j4];
    ((float4*)zq_st)[q] = v;
    ((float4*)zq_all)[q] = v;
    const float4 z = ((const float4*)z_e)[q];
    const float dx = z.x - v.x, dy = z.y - v.y, dz = z.z - v.z, dw = z.w - v.w;
    local += dx * dx + dy * dy + dz * dz + dw * dw;
  }
#pragma unroll
  for (int off = 32; off > 0; off >>= 1) local += __shfl_down(local, off, 64);
  __shared__ float red[4];
  const int w = threadIdx.x >> 6, lane = threadIdx.x & 63;
  if (lane == 0) red[w] = local;
  __syncthreads();
  if (threadIdx.x == 0) atomicAdd(loss_acc, (red[0] + red[1]) + (red[2] + red[3]));
}

// ---------------------------------------------------------------------------
// Kernel 4: finalize losses (sum -> mean; both losses identical forward).
// ---------------------------------------------------------------------------
__global__ void k_scal(float* __restrict__ scal) {
  if (threadIdx.x == 0) {
    const float m = scal[0] * (1.0f / 16777216.0f);
    scal[0] = m;   // codebook_loss
    scal[1] = m;   // commit_loss
  }
}

extern "C" void kernel_launch(void* const* d_in, const int* in_sizes, int n_in,
                              void* d_out, int out_size, void* d_ws, size_t ws_size,
                              hipStream_t stream) {
  const float* z_e = (const float*)d_in[0];
  const float* cb = (const float*)d_in[1];
  float* out = (float*)d_out;

  int* counts = (int*)(out + OFF_ZQ_ALL);   // scratch inside z_q_all region
  float* scal = out + OFF_SCAL;

  hipMemsetAsync(counts, 0, KCB * SCB * sizeof(int), stream);
  hipMemsetAsync(scal, 0, 3 * sizeof(float), stream);

  dim3 g1(NVEC / 256, KCB);
  k_argmin<<<g1, 256, 0, stream>>>(z_e, cb, out, counts);
  k_perp<<<1, 256, 0, stream>>>(counts, scal + 2);
  k_gather<<<1024, 256, 0, stream>>>(z_e, cb, out, out + OFF_ZQ_ST,
                                     out + OFF_ZQ_ALL, scal);
  k_scal<<<1, 64, 0, stream>>>(scal);
}

// Round 5
// 719.472 us; speedup vs baseline: 3.6518x; 3.6518x over previous
//
#include <hip/hip_runtime.h>
#include <math.h>

// Problem constants
#define NVEC  32768          // B*L = 64*512
#define DDIM  512            // CODE_DIM
#define KCB   4              // NUM_CODEBOOKS
#define SCB   1024           // CODEBOOK_SIZE
#define SUBD  128            // SUB_DIM

#define IDX_COUNT (NVEC * KCB)            // 131072
#define ZQ_COUNT  (NVEC * DDIM)           // 16777216
#define OFF_ZQ_ST  IDX_COUNT
#define OFF_ZQ_ALL (IDX_COUNT + ZQ_COUNT)
#define OFF_SCAL   (IDX_COUNT + 2 * ZQ_COUNT)

// Scratch layout inside the z_q_all output region (all consumed before
// k_gather overwrites it; d_ws unused):
//   counts : int  [4096]              at zq_all + 0       (floats)
//   c2s    : f32  [4096] (scaled 2^20) at zq_all + 4096
//   c2np   : f32  [4096] (np-exact)    at zq_all + 8192
//   cb16   : fp16 [4096][128] (x1024)  at zq_all + 12288   (1 MB)
//   cand   : u16  [131072][8]          at zq_all + 274432  (2 MB)

typedef _Float16 v2h __attribute__((ext_vector_type(2)));
union U32H2 { unsigned int u; v2h h; };
__device__ __forceinline__ v2h as_h2(unsigned int u) { U32H2 t; t.u = u; return t.h; }

#if __has_builtin(__builtin_amdgcn_fdot2)
__device__ __forceinline__ float fdot2(v2h a, v2h b, float c) {
  return __builtin_amdgcn_fdot2(a, b, c, false);
}
#else
__device__ __forceinline__ float fdot2(v2h a, v2h b, float c) {
  return fmaf((float)a.y, (float)b.y, fmaf((float)a.x, (float)b.x, c));
}
#endif

// Strict (non-contractable) f32 ops replicating numpy's rounding exactly.
__device__ __forceinline__ float fmul(float a, float b) { return __fmul_rn(a, b); }
__device__ __forceinline__ float fadd(float a, float b) { return __fadd_rn(a, b); }
__device__ __forceinline__ float fsub(float a, float b) { return __fsub_rn(a, b); }

// numpy pairwise_sum for n=128 (scalar 8-accumulator path); elements are
// individually-rounded f32 products. Validated in round 4 (PASS).
__device__ __forceinline__ float np_dot128(const float* __restrict__ u,
                                           const float* __restrict__ v) {
  float r[8];
#pragma unroll
  for (int j = 0; j < 8; ++j) r[j] = fmul(u[j], v[j]);
#pragma unroll
  for (int i = 8; i < 128; i += 8) {
#pragma unroll
    for (int j = 0; j < 8; ++j) r[j] = fadd(r[j], fmul(u[i + j], v[i + j]));
  }
  return fadd(fadd(fadd(r[0], r[1]), fadd(r[2], r[3])),
              fadd(fadd(r[4], r[5]), fadd(r[6], r[7])));
}

// ---------------------------------------------------------------------------
// k_convert: codebook f32 -> fp16 (x1024, kills subnormals) + approx C2*2^20.
// One wave per 16 codes; lanes split the 128 dims (2 each).
// ---------------------------------------------------------------------------
__global__ __launch_bounds__(256) void k_convert(
    const float* __restrict__ cb, unsigned int* __restrict__ cb16,
    float* __restrict__ c2s) {
  const int wave = blockIdx.x * 4 + (threadIdx.x >> 6);
  const int lane = threadIdx.x & 63;
  for (int i = 0; i < 16; ++i) {
    const int code = wave * 16 + i;   // 0..4095
    const float2 v = ((const float2*)(cb + (size_t)code * SUBD))[lane];
    float tot = fmaf(v.x, v.x, v.y * v.y);
#pragma unroll
    for (int off = 32; off > 0; off >>= 1) tot += __shfl_down(tot, off, 64);
    v2h h; h.x = (_Float16)(v.x * 1024.0f); h.y = (_Float16)(v.y * 1024.0f);
    U32H2 t; t.h = h;
    cb16[(size_t)code * 64 + lane] = t.u;
    if (lane == 0) c2s[code] = tot * 1048576.0f;  // * 2^20
  }
}

// ---------------------------------------------------------------------------
// k_c2np: np-exact ||c||^2 per code (same tree as round-4's rescore).
// ---------------------------------------------------------------------------
__global__ __launch_bounds__(256) void k_c2np(const float* __restrict__ cb,
                                              float* __restrict__ c2np) {
  const int c = blockIdx.x * 256 + threadIdx.x;  // 0..4095
  const float* row = cb + (size_t)c * SUBD;
  c2np[c] = np_dot128(row, row);
}

// ---------------------------------------------------------------------------
// k_scan: fp16 dot2 ranking scan. Each block: 256 vectors x one codebook x
// one 512-code half. Codebook tiles (64 codes, 16 KB fp16) staged in LDS;
// inner loop = 16 broadcast ds_read_b128 + 64 v_dot2 (4 chains).
// Emits per-(n,k,half) top-4 candidate indices.
// ---------------------------------------------------------------------------
__global__ __launch_bounds__(256) void k_scan(
    const float* __restrict__ z_e, const uint4* __restrict__ cb16,
    const float* __restrict__ c2s, unsigned short* __restrict__ cand) {
  const int tid = threadIdx.x;
  const int k = blockIdx.y;
  const int half = blockIdx.z;
  const int n = blockIdx.x * 256 + tid;

  __shared__ uint4 ctile[1024];   // 64 codes * 256 B
  __shared__ float c2t[64];

  // x -> 64 half2 registers (scan precision only).
  v2h x2[64];
  {
    const float2* xp = (const float2*)(z_e + (size_t)n * DDIM + k * SUBD);
#pragma unroll
    for (int j = 0; j < 64; ++j) {
      const float2 f = xp[j];
      v2h h; h.x = (_Float16)f.x; h.y = (_Float16)f.y;
      x2[j] = h;
    }
  }

  float m0 = 1e30f, m1 = 1e30f, m2 = 1e30f, m3 = 1e30f;
  int i0 = 0, i1 = 0, i2 = 0, i3 = 0;

  for (int t = 0; t < 8; ++t) {
    const int base = half * 512 + t * 64;
    const uint4* gsrc = cb16 + (size_t)(k * SCB + base) * 16;
    __syncthreads();
#pragma unroll
    for (int i = 0; i < 4; ++i) ctile[tid + i * 256] = gsrc[tid + i * 256];
    if (tid < 64) c2t[tid] = c2s[k * SCB + base + tid];
    __syncthreads();

    for (int sl = 0; sl < 64; ++sl) {
      const uint4* crow = ctile + sl * 16;
      float a0 = 0.f, a1 = 0.f, a2 = 0.f, a3 = 0.f;
#pragma unroll
      for (int i = 0; i < 16; ++i) {
        const uint4 q = crow[i];
        a0 = fdot2(as_h2(q.x), x2[4 * i + 0], a0);
        a1 = fdot2(as_h2(q.y), x2[4 * i + 1], a1);
        a2 = fdot2(as_h2(q.z), x2[4 * i + 2], a2);
        a3 = fdot2(as_h2(q.w), x2[4 * i + 3], a3);
      }
      // scaled score = 2^20 * (C2 - 2*dot):  D ~ 1024*dot
      const float score = fmaf(-2048.0f, (a0 + a1) + (a2 + a3), c2t[sl]);
      const int s = base + sl;
      if (score < m3) {
        if (score < m0)      { m3=m2;i3=i2; m2=m1;i2=i1; m1=m0;i1=i0; m0=score;i0=s; }
        else if (score < m1) { m3=m2;i3=i2; m2=m1;i2=i1; m1=score;i1=s; }
        else if (score < m2) { m3=m2;i3=i2; m2=score;i2=s; }
        else                 { m3=score;i3=s; }
      }
    }
  }

  unsigned short* cp = cand + ((size_t)(n * KCB + k)) * 8 + half * 4;
  cp[0] = (unsigned short)i0; cp[1] = (unsigned short)i1;
  cp[2] = (unsigned short)i2; cp[3] = (unsigned short)i3;
}

// ---------------------------------------------------------------------------
// k_merge: np-exact f32 rescore of the 8 candidates per (n,k); same formula/
// tree as round 4 (validated). Writes final index + counts.
// ---------------------------------------------------------------------------
__global__ __launch_bounds__(256) void k_merge(
    const float* __restrict__ z_e, const float* __restrict__ cb,
    const unsigned short* __restrict__ cand, const float* __restrict__ c2np,
    float* __restrict__ out_idx, int* __restrict__ counts) {
  const int g = blockIdx.x * 256 + threadIdx.x;  // 0..131071
  const int n = g >> 2, k = g & 3;

  float4 xv[32];
  const float4* xp = (const float4*)(z_e + (size_t)n * DDIM + k * SUBD);
#pragma unroll
  for (int j = 0; j < 32; ++j) xv[j] = xp[j];
  const float* xs = (const float*)xv;
  const float A = np_dot128(xs, xs);

  const unsigned short* cp = cand + (size_t)g * 8;
  float bd = 1e30f;
  int bi = SCB;
#pragma unroll
  for (int t = 0; t < 8; ++t) {
    const int s = cp[t];
    const float* c = cb + (size_t)(k * SCB + s) * SUBD;
    const float E = np_dot128(xs, c);
    const float dist = fadd(fsub(A, fmul(2.0f, E)), c2np[k * SCB + s]);
    if (dist < bd || (dist == bd && s < bi)) { bd = dist; bi = s; }
  }

  out_idx[g] = (float)bi;
  atomicAdd(&counts[k * SCB + bi], 1);
}

// ---------------------------------------------------------------------------
// k_perp: perplexity from counts (before k_gather overwrites counts region).
// ---------------------------------------------------------------------------
__global__ __launch_bounds__(256) void k_perp(const int* __restrict__ counts,
                                              float* __restrict__ out_perp) {
  const int w = threadIdx.x >> 6;
  const int lane = threadIdx.x & 63;
  double h = 0.0;
  for (int i = 0; i < SCB / 64; ++i) {
    const int cnt = counts[w * SCB + i * 64 + lane];
    if (cnt > 0) {
      const double p = (double)cnt * (1.0 / 32768.0);
      h += p * log(p);
    }
  }
#pragma unroll
  for (int off = 32; off > 0; off >>= 1) h += __shfl_down(h, off, 64);
  __shared__ double hs[4];
  if (lane == 0) hs[w] = h;
  __syncthreads();
  if (threadIdx.x == 0) {
    double perp = 0.0;
    for (int w2 = 0; w2 < 4; ++w2) perp += exp(-hs[w2]);
    out_perp[0] = (float)(perp * 0.25);
  }
}

// ---------------------------------------------------------------------------
// k_gather: coalesced gather of z_q into both output slots + loss partial.
// ---------------------------------------------------------------------------
__global__ __launch_bounds__(256) void k_gather(
    const float* __restrict__ z_e, const float* __restrict__ cb,
    const float* __restrict__ idxf, float* __restrict__ zq_st,
    float* __restrict__ zq_all, float* __restrict__ loss_acc) {
  const int base = blockIdx.x * 4096;
  float local = 0.f;
#pragma unroll
  for (int i = 0; i < 16; ++i) {
    const int q = base + i * 256 + threadIdx.x;
    const int nn = q >> 7;
    const int rem = q & 127;
    const int kk = rem >> 5;
    const int j4 = rem & 31;
    const int idx = (int)idxf[nn * KCB + kk];
    const float4 v = ((const float4*)cb)[(size_t)(kk * SCB + idx) * 32 + j4];
    ((float4*)zq_st)[q] = v;
    ((float4*)zq_all)[q] = v;
    const float4 z = ((const float4*)z_e)[q];
    const float dx = z.x - v.x, dy = z.y - v.y, dz = z.z - v.z, dw = z.w - v.w;
    local += dx * dx + dy * dy + dz * dz + dw * dw;
  }
#pragma unroll
  for (int off = 32; off > 0; off >>= 1) local += __shfl_down(local, off, 64);
  __shared__ float red[4];
  const int w = threadIdx.x >> 6, lane = threadIdx.x & 63;
  if (lane == 0) red[w] = local;
  __syncthreads();
  if (threadIdx.x == 0) atomicAdd(loss_acc, (red[0] + red[1]) + (red[2] + red[3]));
}

__global__ void k_scal(float* __restrict__ scal) {
  if (threadIdx.x == 0) {
    const float m = scal[0] * (1.0f / 16777216.0f);
    scal[0] = m;   // codebook_loss
    scal[1] = m;   // commit_loss
  }
}

extern "C" void kernel_launch(void* const* d_in, const int* in_sizes, int n_in,
                              void* d_out, int out_size, void* d_ws, size_t ws_size,
                              hipStream_t stream) {
  const float* z_e = (const float*)d_in[0];
  const float* cb = (const float*)d_in[1];
  float* out = (float*)d_out;

  float* zq_all = out + OFF_ZQ_ALL;
  int* counts = (int*)zq_all;
  float* c2s = zq_all + 4096;
  float* c2np = zq_all + 8192;
  unsigned int* cb16 = (unsigned int*)(zq_all + 12288);
  unsigned short* cand = (unsigned short*)(zq_all + 274432);
  float* scal = out + OFF_SCAL;

  hipMemsetAsync(counts, 0, KCB * SCB * sizeof(int), stream);
  hipMemsetAsync(scal, 0, 3 * sizeof(float), stream);

  k_convert<<<64, 256, 0, stream>>>(cb, cb16, c2s);
  k_c2np<<<16, 256, 0, stream>>>(cb, c2np);
  dim3 gs(NVEC / 256, KCB, 2);
  k_scan<<<gs, 256, 0, stream>>>(z_e, (const uint4*)cb16, c2s, cand);
  k_merge<<<IDX_COUNT / 256, 256, 0, stream>>>(z_e, cb, cand, c2np, out, counts);
  k_perp<<<1, 256, 0, stream>>>(counts, scal + 2);
  k_gather<<<1024, 256, 0, stream>>>(z_e, cb, out, out + OFF_ZQ_ST, zq_all, scal);
  k_scal<<<1, 64, 0, stream>>>(scal);
}